// Round 11
// baseline (239.262 us; speedup 1.0000x reference)
//
#include <hip/hip_runtime.h>
#include <hip/hip_bf16.h>
#include <math.h>

// GAT forward. N=4096, Fin=512, H=8, D=64, C=64.
// Round 11: attn_v6 = register-direct attention. Each WAVE owns a 32(16)-row x
// 64-col tile; p computed straight into the MFMA A-fragment layout (lane c16,kg
// -> row c16, j kg*8+e), packed via v_cvt_pk_bf16_f32. NO LDS, NO barriers.
// Masks precomputed in A-fragment bit order (mbA) so masking stays one
// v_cndmask with an SGPR word. attn1 uses the same kernel; combine1T+lsm_row
// replace the old LDS-heavy epilogue. adj read once (mbA only).

#define N_NODES 4096
#define FIN 512
#define NHEAD 8
#define DHEAD 64
#define NCLS 64

typedef unsigned short u16;
typedef unsigned long long u64;
typedef __attribute__((ext_vector_type(8))) short bf16x8;
typedef __attribute__((ext_vector_type(4))) float f32x4;

__device__ __forceinline__ float lrelu02(float x) { return x > 0.f ? x : 0.2f * x; }
__device__ __forceinline__ u16 bf16u(float x) {
    __hip_bfloat16 h = __float2bfloat16(x);
    return __builtin_bit_cast(unsigned short, h);
}
__device__ __forceinline__ f32x4 mfma16(bf16x8 a, bf16x8 b, f32x4 c) {
    return __builtin_amdgcn_mfma_f32_16x16x32_bf16(a, b, c, 0, 0, 0);
}
__device__ __forceinline__ unsigned fkey(float f) {
    unsigned u = __builtin_bit_cast(unsigned, f);
    return (u & 0x80000000u) ? ~u : (u | 0x80000000u);
}
__device__ __forceinline__ float funkey(unsigned k) {
    unsigned u = (k & 0x80000000u) ? (k ^ 0x80000000u) : ~k;
    return __builtin_bit_cast(float, u);
}

// ---------------- prep: cvts, mbA (A-fragment-order masks), weight T ---------
// mbA[g][jt][w]: bit b = adj(g*16+(b&15), jt*64+(b>>4)*8+(w>>3)*32+(w&7)) > 0
__global__ __launch_bounds__(256) void prep(
    const int* __restrict__ adj, u64* __restrict__ mbA, unsigned* __restrict__ gmk,
    const float* __restrict__ x, u16* __restrict__ xB,
    const float* __restrict__ W1, u16* __restrict__ W1B,
    const float* __restrict__ W, const float* __restrict__ Wo,
    u16* __restrict__ WBt, u16* __restrict__ WoBt) {
    __shared__ alignas(16) u16 T[64][72];
    const int bid = blockIdx.x, t = threadIdx.x;
    if (bid < 4096) {
        // bf16 converts: x (512K quads) then W1 (512K quads)
        int i = bid * 256 + t;
        const float* s;
        u16* d;
        if (i < N_NODES * FIN / 4) { s = x; d = xB; }
        else { i -= N_NODES * FIN / 4; s = W1; d = W1B; }
        float4 v = ((const float4*)s)[i];
        ushort4 o = {bf16u(v.x), bf16u(v.y), bf16u(v.z), bf16u(v.w)};
        ((ushort4*)d)[i] = o;
    } else if (bid < 8192) {
        if (bid == 4096 && t < 16) gmk[t] = 0u;
        const int lane = t & 63;
        const int task = (bid - 4096) * 4 + (t >> 6);  // (g, jt)
        const int g = task >> 6, jt = task & 63;
        const int r = lane & 15, kq = lane >> 4;
        const int* ap = adj + (size_t)(g * 16 + r) * N_NODES + jt * 64 + kq * 8;
        int4 c0 = *(const int4*)(ap);
        int4 c1 = *(const int4*)(ap + 4);
        int4 c2 = *(const int4*)(ap + 32);
        int4 c3 = *(const int4*)(ap + 36);
        u64 myw = 0;
        #pragma unroll
        for (int w = 0; w < 16; ++w) {
            const int hf = w >> 3, i = w & 7;
            int val;
            if (hf == 0) val = (i < 4) ? ((const int*)&c0)[i & 3] : ((const int*)&c1)[i & 3];
            else         val = (i < 4) ? ((const int*)&c2)[i & 3] : ((const int*)&c3)[i & 3];
            u64 bal = __ballot(val > 0);
            if (lane == w) myw = bal;
        }
        if (lane < 16) mbA[((size_t)g * 64 + jt) * 16 + lane] = myw;
    } else {
        // weight transposes: W[8][512][64] and Wo[512][64] -> [d][k] bf16
        int idx = bid - 8192;
        int y = idx >> 3, xb = idx & 7;
        const float* src = (y < 8) ? W + (size_t)y * FIN * DHEAD : Wo;
        u16* d = (y < 8) ? WBt + (size_t)y * DHEAD * FIN : WoBt;
        const int j0 = xb * 64;
        const int row = t & 63, g = t >> 6;
        #pragma unroll
        for (int k = 0; k < 16; k += 4) {
            float4 v = *(const float4*)(src + (size_t)(j0 + row) * 64 + g * 16 + k);
            T[g * 16 + k + 0][row] = bf16u(v.x);
            T[g * 16 + k + 1][row] = bf16u(v.y);
            T[g * 16 + k + 2][row] = bf16u(v.z);
            T[g * 16 + k + 3][row] = bf16u(v.w);
        }
        __syncthreads();
        const int dd = t >> 2, jc = (t & 3) * 16;
        *(uint4*)(d + (size_t)dd * FIN + j0 + jc) = *(const uint4*)&T[dd][jc];
        *(uint4*)(d + (size_t)dd * FIN + j0 + jc + 8) = *(const uint4*)&T[dd][jc + 8];
    }
}

// ---------------- fused MFMA GEMM (x@W / h@Wo + f1/f2 + gmax + bf16-T out) ----
__global__ __launch_bounds__(256) void gemm_fused(
    const u16* __restrict__ A, int lda, const u16* __restrict__ Bt, int ldb,
    const float* __restrict__ a1a, const float* __restrict__ a2a,
    u16* __restrict__ WhBT, float* __restrict__ f1o, float* __restrict__ f2o,
    unsigned* __restrict__ gmk, int K) {
    __shared__ alignas(16) u16 T[64][72];
    const int t = threadIdx.x, lane = t & 63, wv = t >> 6;
    const int c16 = lane & 15, kg = lane >> 4;
    const int h = blockIdx.x;
    const int bm = blockIdx.y * 64;
    const u16* Ap = A + (size_t)(bm + wv * 16 + c16) * lda + kg * 8;
    const u16* Bp = Bt + (size_t)(h * 64 + c16) * ldb + kg * 8;
    f32x4 acc[4] = {};
    #pragma unroll 4
    for (int k0 = 0; k0 < K; k0 += 32) {
        bf16x8 a = *(const bf16x8*)(Ap + k0);
        #pragma unroll
        for (int ct = 0; ct < 4; ++ct) {
            bf16x8 b = *(const bf16x8*)(Bp + (size_t)ct * 16 * ldb + k0);
            acc[ct] = mfma16(a, b, acc[ct]);
        }
    }
    float a1v[4], a2v[4];
    #pragma unroll
    for (int ct = 0; ct < 4; ++ct) {
        a1v[ct] = a1a[h * 64 + ct * 16 + c16];
        a2v[ct] = a2a[h * 64 + ct * 16 + c16];
    }
    float mx = -1e30f;
    #pragma unroll
    for (int r = 0; r < 4; ++r) {
        float s1 = 0.f, s2 = 0.f;
        int rl = wv * 16 + kg * 4 + r;
        #pragma unroll
        for (int ct = 0; ct < 4; ++ct) {
            float v = acc[ct][r];
            s1 = fmaf(v, a1v[ct], s1);
            s2 = fmaf(v, a2v[ct], s2);
            T[ct * 16 + c16][rl] = bf16u(v);
        }
        #pragma unroll
        for (int off = 1; off < 16; off <<= 1) {
            s1 += __shfl_xor(s1, off, 64);
            s2 += __shfl_xor(s2, off, 64);
        }
        if (c16 == 0) {
            f1o[(size_t)h * N_NODES + bm + rl] = s1;
            f2o[(size_t)h * N_NODES + bm + rl] = s2;
        }
        mx = fmaxf(mx, s2);
    }
    mx = fmaxf(mx, __shfl_xor(mx, 16, 64));
    mx = fmaxf(mx, __shfl_xor(mx, 32, 64));
    if (lane == 0) atomicMax(&gmk[h], fkey(mx));
    __syncthreads();
    const int dd = t >> 2, jc = (t & 3) * 16;
    u16* dst = WhBT + (size_t)(h * 64 + dd) * N_NODES + bm;
    *(uint4*)(dst + jc) = *(const uint4*)&T[dd][jc];
    *(uint4*)(dst + jc + 8) = *(const uint4*)&T[dd][jc + 8];
}

// ---------------- per-row / per-col softmax coefficients ----------------
__global__ void coefk(const float* __restrict__ f1, const float* __restrict__ f2,
                      const unsigned* __restrict__ gmk, float2* __restrict__ rowc,
                      float2* __restrict__ uv) {
    int h = blockIdx.y;
    int i = blockIdx.x * 256 + threadIdx.x;
    float g = funkey(gmk[h]);
    float a = f1[(size_t)h * N_NODES + i];
    float s = a + g;
    float M = lrelu02(s);
    rowc[(size_t)h * N_NODES + i] = make_float2(__expf(s - M), __expf(0.2f * s - M));
    float b = f2[(size_t)h * N_NODES + i] - g;
    uv[(size_t)h * N_NODES + i] = make_float2(__expf(b), __expf(0.2f * b));
}

// ---------------- attention v6: register-direct, wave-independent ------------
// Wave owns MT*16 rows x 64 cols x its j-range. p built in A-fragment layout;
// no LDS, no barriers. Output: fp32 row-major partial [js][4096][OC].
template <int NH, int MT, int JSPLIT, int LJS>
__global__ __launch_bounds__(256) void attn_v6(
    const u16* __restrict__ WhB, const float2* __restrict__ uv,
    const float2* __restrict__ rowc, const u64* __restrict__ mbA,
    float* __restrict__ outp, float* __restrict__ denP) {
    constexpr int NJT = 64 / JSPLIT;
    constexpr int OC = (NH == 8) ? 512 : 64;
    const int t = threadIdx.x, lane = t & 63;
    const int gw = __builtin_amdgcn_readfirstlane(blockIdx.x * 4 + (t >> 6));
    int h, ib, js;
    if (NH == 8) { h = gw & 7; int rest = gw >> 3; js = rest & (JSPLIT - 1); ib = rest >> LJS; }
    else { h = 0; js = gw & (JSPLIT - 1); ib = gw >> LJS; }
    const int i0 = ib * (MT * 16);
    const int g0 = i0 >> 4;
    const int jt0 = js * NJT;
    const int kg = lane >> 4, c16 = lane & 15;

    const float* uvf = (const float*)(uv + (size_t)h * N_NODES);
    const float2* rcp = rowc + (size_t)h * N_NODES;

    float Aq[MT], Bq[MT], den[MT];
    #pragma unroll
    for (int mt = 0; mt < MT; ++mt) {
        float2 rc = rcp[i0 + mt * 16 + c16];
        Aq[mt] = rc.x; Bq[mt] = rc.y; den[mt] = 0.f;
    }
    const u16* bp[4];
    #pragma unroll
    for (int ct = 0; ct < 4; ++ct)
        bp[ct] = WhB + ((size_t)h * 64 + ct * 16 + c16) * N_NODES + kg * 8;

    f32x4 acc[MT][4] = {};

    for (int it = 0; it < NJT; ++it) {
        const int jt = jt0 + it;
        // uv loads: 8 j-pairs per half (u,v interleaved float2)
        const float* up = uvf + (size_t)(jt * 64 + kg * 8) * 2;
        float4 u0[4], u1[4];
        #pragma unroll
        for (int k = 0; k < 4; ++k) {
            u0[k] = *(const float4*)(up + k * 4);
            u1[k] = *(const float4*)(up + 64 + k * 4);
        }
        // B fragments
        bf16x8 bfr[4][2];
        #pragma unroll
        for (int ct = 0; ct < 4; ++ct) {
            bfr[ct][0] = *(const bf16x8*)(bp[ct] + (size_t)jt * 64);
            bfr[ct][1] = *(const bf16x8*)(bp[ct] + (size_t)jt * 64 + 32);
        }
        #pragma unroll
        for (int mt = 0; mt < MT; ++mt) {
            const u64* mw = mbA + ((size_t)(g0 + mt) * 64 + jt) * 16;
            unsigned pk[8];
            #pragma unroll
            for (int hf = 0; hf < 2; ++hf) {
                #pragma unroll
                for (int k = 0; k < 4; ++k) {
                    float4 q = hf ? u1[k] : u0[k];
                    u64 w0 = mw[hf * 8 + 2 * k];
                    u64 w1 = mw[hf * 8 + 2 * k + 1];
                    unsigned l0 = __builtin_amdgcn_readfirstlane((unsigned)w0);
                    unsigned h0 = __builtin_amdgcn_readfirstlane((unsigned)(w0 >> 32));
                    unsigned l1 = __builtin_amdgcn_readfirstlane((unsigned)w1);
                    unsigned h1 = __builtin_amdgcn_readfirstlane((unsigned)(w1 >> 32));
                    u64 ws0 = ((u64)h0 << 32) | l0;
                    u64 ws1 = ((u64)h1 << 32) | l1;
                    float t0 = fmaxf(Aq[mt] * q.x, Bq[mt] * q.y);
                    float t1 = fmaxf(Aq[mt] * q.z, Bq[mt] * q.w);
                    float p0, p1;
                    asm("v_cndmask_b32 %0, 0, %1, %2" : "=v"(p0) : "v"(t0), "s"(ws0));
                    asm("v_cndmask_b32 %0, 0, %1, %2" : "=v"(p1) : "v"(t1), "s"(ws1));
                    den[mt] += p0 + p1;
                    unsigned pkd;
                    asm("v_cvt_pk_bf16_f32 %0, %1, %2" : "=v"(pkd) : "v"(p0), "v"(p1));
                    pk[hf * 4 + k] = pkd;
                }
            }
            union { unsigned d[4]; bf16x8 v; } ua, ub;
            #pragma unroll
            for (int k = 0; k < 4; ++k) { ua.d[k] = pk[k]; ub.d[k] = pk[4 + k]; }
            #pragma unroll
            for (int ct = 0; ct < 4; ++ct) {
                acc[mt][ct] = mfma16(ua.v, bfr[ct][0], acc[mt][ct]);
                acc[mt][ct] = mfma16(ub.v, bfr[ct][1], acc[mt][ct]);
            }
        }
    }

    // den: reduce over kg groups (lanes sharing c16)
    #pragma unroll
    for (int mt = 0; mt < MT; ++mt) {
        den[mt] += __shfl_xor(den[mt], 16, 64);
        den[mt] += __shfl_xor(den[mt], 32, 64);
    }
    float* denDst = (NH == 8) ? denP + (size_t)js * (8 * N_NODES) + (size_t)h * N_NODES
                              : denP + (size_t)js * N_NODES;
    if (lane < 16) {
        #pragma unroll
        for (int mt = 0; mt < MT; ++mt) denDst[i0 + mt * 16 + lane] = den[mt];
    }
    float* dst = outp + (size_t)js * N_NODES * OC + h * 64;
    #pragma unroll
    for (int mt = 0; mt < MT; ++mt)
        #pragma unroll
        for (int ct = 0; ct < 4; ++ct)
            #pragma unroll
            for (int r = 0; r < 4; ++r)
                dst[(size_t)(i0 + mt * 16 + kg * 4 + r) * OC + ct * 16 + c16] = acc[mt][ct][r];
}

// ---------------- combine attn8 partials (2-way) -> bf16 hB ----------------
__global__ __launch_bounds__(256) void combine8(
    const float* __restrict__ part, const float* __restrict__ denp,
    u16* __restrict__ hB) {
    const int t4 = (blockIdx.x * 256 + threadIdx.x) * 4;
    const int i = t4 >> 9, c = t4 & 511, h = c >> 6;
    float4 p0 = *(const float4*)(part + t4);
    float4 p1 = *(const float4*)(part + (size_t)N_NODES * 512 + t4);
    float d = denp[h * N_NODES + i] + denp[8 * N_NODES + h * N_NODES + i];
    float inv = d > 0.f ? 1.f / d : 0.f;
    float v[4] = {(p0.x + p1.x) * inv, (p0.y + p1.y) * inv,
                  (p0.z + p1.z) * inv, (p0.w + p1.w) * inv};
    ushort4 o;
    #pragma unroll
    for (int k = 0; k < 4; ++k) {
        float e = v[k] > 0.f ? v[k] : expm1f(v[k]);
        ((u16*)&o)[k] = bf16u(e);
    }
    *(ushort4*)(hB + t4) = o;
}

// ---------------- combine attn1 partials (8-way) + ELU -> transposed fp32 ----
__global__ __launch_bounds__(256) void combine1T(
    const float* __restrict__ part1, const float* __restrict__ den1,
    float* __restrict__ attoutT) {
    __shared__ float T[64][65];
    const int b = blockIdx.x, t = threadIdx.x;
    const int r0 = b * 64;
    const int rl = t >> 2, cg = (t & 3) * 16;
    const int row = r0 + rl;
    float d = 0.f;
    #pragma unroll
    for (int js = 0; js < 8; ++js) d += den1[(size_t)js * N_NODES + row];
    float inv = d > 0.f ? 1.f / d : 0.f;
    float s[16] = {};
    #pragma unroll
    for (int js = 0; js < 8; ++js) {
        const float* p = part1 + (size_t)js * N_NODES * 64 + (size_t)row * 64 + cg;
        #pragma unroll
        for (int k = 0; k < 16; k += 4) {
            float4 v = *(const float4*)(p + k);
            s[k] += v.x; s[k + 1] += v.y; s[k + 2] += v.z; s[k + 3] += v.w;
        }
    }
    #pragma unroll
    for (int k = 0; k < 16; ++k) {
        float e = s[k] * inv;
        T[rl][cg + k] = e > 0.f ? e : expm1f(e);
    }
    __syncthreads();
    const int c = t >> 2, seg = (t & 3) * 16;
    #pragma unroll
    for (int k = 0; k < 16; k += 4) {
        float4 v = {T[seg + k][c], T[seg + k + 1][c], T[seg + k + 2][c], T[seg + k + 3][c]};
        *(float4*)(attoutT + (size_t)c * N_NODES + r0 + seg + k) = v;
    }
}

// ---------------- row log_softmax on attoutT, emit bf16 lsT ----------------
__global__ __launch_bounds__(256) void lsm_row(const float* __restrict__ aT,
                                               u16* __restrict__ lsT) {
    int c = blockIdx.x, t = threadIdx.x;
    const float* row = aT + (size_t)c * N_NODES;
    __shared__ float r[256];
    float m = -1e30f;
    for (int i = t * 4; i < N_NODES; i += 1024) {
        float4 v = *(const float4*)(row + i);
        m = fmaxf(fmaxf(fmaxf(m, v.x), fmaxf(v.y, v.z)), v.w);
    }
    r[t] = m;
    __syncthreads();
    for (int s = 128; s; s >>= 1) {
        if (t < s) r[t] = fmaxf(r[t], r[t + s]);
        __syncthreads();
    }
    m = r[0];
    __syncthreads();
    float sum = 0.f;
    for (int i = t * 4; i < N_NODES; i += 1024) {
        float4 v = *(const float4*)(row + i);
        sum += __expf(v.x - m) + __expf(v.y - m) + __expf(v.z - m) + __expf(v.w - m);
    }
    r[t] = sum;
    __syncthreads();
    for (int s = 128; s; s >>= 1) {
        if (t < s) r[t] += r[t + s];
        __syncthreads();
    }
    float lse = m + __logf(r[0]);
    for (int i = t * 4; i < N_NODES; i += 1024) {
        float4 v = *(const float4*)(row + i);
        ushort4 o = {bf16u(v.x - lse), bf16u(v.y - lse), bf16u(v.z - lse), bf16u(v.w - lse)};
        *(ushort4*)(lsT + (size_t)c * N_NODES + i) = o;
    }
}

// ---------------- mlp1: split-K MFMA  part[ks][64 c][512 o] ----------------
__global__ __launch_bounds__(256) void mlp1_mfma(
    const u16* __restrict__ lsT, const u16* __restrict__ W1B,
    float* __restrict__ part) {
    const int t = threadIdx.x, lane = t & 63, wv = t >> 6;
    const int c16 = lane & 15, kg = lane >> 4;
    const int ks = blockIdx.x & 15;
    const int bn = (blockIdx.x >> 4) * 64;
    const int kb = ks * 256;
    const u16* Ap = lsT + (size_t)(wv * 16 + c16) * N_NODES + kb + kg * 8;
    const u16* Bp = W1B + (size_t)(bn + c16) * N_NODES + kb + kg * 8;
    f32x4 acc[4] = {};
    #pragma unroll
    for (int k0 = 0; k0 < 256; k0 += 32) {
        bf16x8 a = *(const bf16x8*)(Ap + k0);
        #pragma unroll
        for (int ct = 0; ct < 4; ++ct) {
            bf16x8 b = *(const bf16x8*)(Bp + (size_t)ct * 16 * N_NODES + k0);
            acc[ct] = mfma16(a, b, acc[ct]);
        }
    }
    float* dst = part + (size_t)ks * 64 * 512;
    #pragma unroll
    for (int ct = 0; ct < 4; ++ct)
        #pragma unroll
        for (int r = 0; r < 4; ++r)
            dst[(size_t)(wv * 16 + kg * 4 + r) * 512 + bn + ct * 16 + c16] = acc[ct][r];
}

// ---------------- fused: reduce split-K + bias + leaky, then y @ W2^T --------
__global__ __launch_bounds__(256) void mlp2f(
    const float* __restrict__ part, const float* __restrict__ b1,
    const float* __restrict__ W2, const float* __restrict__ b2,
    float* __restrict__ out) {
    __shared__ alignas(16) float row[512];
    const int c = blockIdx.x, t = threadIdx.x;
    #pragma unroll
    for (int half = 0; half < 2; ++half) {
        int o = t + half * 256;
        float s = 0.f;
        #pragma unroll
        for (int ks = 0; ks < 16; ++ks)
            s += part[(size_t)ks * 32768 + (size_t)c * 512 + o];
        s += b1[o];
        row[o] = s > 0.f ? s : 0.1f * s;
    }
    __syncthreads();
    float acc = 0.f;
    #pragma unroll 4
    for (int o = 0; o < 512; o += 4) {
        float4 w4 = *(const float4*)(W2 + (size_t)t * 512 + o);
        float4 r4 = *(const float4*)(&row[o]);
        acc += w4.x * r4.x + w4.y * r4.y + w4.z * r4.z + w4.w * r4.w;
    }
    out[(size_t)c * 256 + t] = acc + b2[t];
}

extern "C" void kernel_launch(void* const* d_in, const int* in_sizes, int n_in,
                              void* d_out, int out_size, void* d_ws, size_t ws_size,
                              hipStream_t stream) {
    const float* x   = (const float*)d_in[0];
    const int*   adj = (const int*)d_in[1];
    const float* W   = (const float*)d_in[2];
    const float* a1  = (const float*)d_in[3];
    const float* a2  = (const float*)d_in[4];
    const float* Wo  = (const float*)d_in[5];
    const float* ao1 = (const float*)d_in[6];
    const float* ao2 = (const float*)d_in[7];
    const float* W1  = (const float*)d_in[8];
    const float* b1  = (const float*)d_in[9];
    const float* W2  = (const float*)d_in[10];
    const float* b2  = (const float*)d_in[11];
    float* out = (float*)d_out;

    char* ws = (char*)d_ws;
    size_t off = 0;
    auto alloc = [&](size_t bytes) {
        void* p = ws + off;
        off += (bytes + 255) & ~(size_t)255;
        return p;
    };
    u64*     mbA    = (u64*)alloc((size_t)256 * 64 * 16 * 8);          // 2 MB
    u16*     xB     = (u16*)alloc((size_t)N_NODES * FIN * 2);
    u16*     WBt    = (u16*)alloc((size_t)NHEAD * DHEAD * FIN * 2);
    u16*     WoBt   = (u16*)alloc((size_t)DHEAD * FIN * 2);
    u16*     W1B    = (u16*)alloc((size_t)512 * N_NODES * 2);
    u16*     WhB    = (u16*)alloc((size_t)NHEAD * DHEAD * N_NODES * 2);
    u16*     WhoB   = (u16*)alloc((size_t)DHEAD * N_NODES * 2);
    u16*     hB     = (u16*)alloc((size_t)N_NODES * 512 * 2);
    float*   part8  = (float*)alloc((size_t)2 * N_NODES * 512 * 4);    // 16 MB
    float*   den8   = (float*)alloc((size_t)2 * 8 * N_NODES * 4);
    float*   f1b    = (float*)alloc((size_t)9 * N_NODES * 4);
    float*   f2b    = (float*)alloc((size_t)9 * N_NODES * 4);
    unsigned* gmk   = (unsigned*)alloc(16 * 4);
    float2*  rowc   = (float2*)alloc((size_t)9 * N_NODES * 8);
    float2*  uvb    = (float2*)alloc((size_t)9 * N_NODES * 8);
    // layer-2 scratch overlaid on part8 (dead after combine8)
    char*  ov      = (char*)part8;
    float* part1   = (float*)(ov);                          // 8 MB [8][4096][64]
    float* den1    = (float*)(ov + ((size_t)8 << 20));      // 128 KB
    float* attoutT = (float*)(ov + ((size_t)9 << 20));      // 1 MB
    u16*   lsT     = (u16*)(ov + ((size_t)10 << 20));       // 512 KB
    float* part    = (float*)(ov + ((size_t)11 << 20));     // 2 MB
    (void)ws_size; (void)in_sizes; (void)n_in; (void)out_size;

    prep<<<8264, 256, 0, stream>>>(adj, mbA, gmk, x, xB, W1, W1B, W, Wo, WBt, WoBt);
    // layer 1
    gemm_fused<<<dim3(8, 64), 256, 0, stream>>>(xB, FIN, WBt, FIN, a1, a2,
                                                WhB, f1b, f2b, gmk, FIN);
    coefk<<<dim3(16, 8), 256, 0, stream>>>(f1b, f2b, gmk, rowc, uvb);
    // 2048 waves: 8 h x 128 ib (32 rows) x 2 js
    attn_v6<8, 2, 2, 1><<<512, 256, 0, stream>>>(WhB, uvb, rowc, mbA, part8, den8);
    combine8<<<N_NODES * 512 / 4 / 256, 256, 0, stream>>>(part8, den8, hB);
    // layer 2
    gemm_fused<<<dim3(1, 64), 256, 0, stream>>>(hB, 512, WoBt, FIN, ao1, ao2,
                                                WhoB, f1b + (size_t)8 * N_NODES,
                                                f2b + (size_t)8 * N_NODES, gmk + 8, FIN);
    coefk<<<dim3(16, 1), 256, 0, stream>>>(f1b + (size_t)8 * N_NODES,
                                           f2b + (size_t)8 * N_NODES, gmk + 8,
                                           rowc + (size_t)8 * N_NODES,
                                           uvb + (size_t)8 * N_NODES);
    // 2048 waves: 256 ib (16 rows) x 8 js
    attn_v6<1, 1, 8, 3><<<512, 256, 0, stream>>>(
        WhoB, uvb + (size_t)8 * N_NODES, rowc + (size_t)8 * N_NODES, mbA, part1, den1);
    combine1T<<<64, 256, 0, stream>>>(part1, den1, attoutT);
    lsm_row<<<64, 256, 0, stream>>>(attoutT, lsT);
    // MLP head
    mlp1_mfma<<<128, 256, 0, stream>>>(lsT, W1B, part);
    mlp2f<<<64, 256, 0, stream>>>(part, b1, W2, b2, out);
}

// Round 12
// 234.803 us; speedup vs baseline: 1.0190x; 1.0190x over previous
//
#include <hip/hip_runtime.h>
#include <hip/hip_bf16.h>
#include <math.h>

// GAT forward. N=4096, Fin=512, H=8, D=64, C=64.
// Round 12: attn_v6 (register-direct, no LDS/barriers) kept; fix = OCCUPANCY.
//  - attn8 JSPLIT 2->8 (8192 waves = 32/CU, was 8/CU), attn1 JSPLIT 16 (4096).
//  - partials stored bf16 (halves the extra HBM traffic the split costs).
//  - head = blockIdx&7 -> per-head B-slice pinned to one XCD L2.

#define N_NODES 4096
#define FIN 512
#define NHEAD 8
#define DHEAD 64
#define NCLS 64

typedef unsigned short u16;
typedef unsigned long long u64;
typedef __attribute__((ext_vector_type(8))) short bf16x8;
typedef __attribute__((ext_vector_type(4))) float f32x4;

__device__ __forceinline__ float lrelu02(float x) { return x > 0.f ? x : 0.2f * x; }
__device__ __forceinline__ u16 bf16u(float x) {
    __hip_bfloat16 h = __float2bfloat16(x);
    return __builtin_bit_cast(unsigned short, h);
}
__device__ __forceinline__ float b2f(u16 v) {
    unsigned u = (unsigned)v << 16;
    return __builtin_bit_cast(float, u);
}
__device__ __forceinline__ f32x4 mfma16(bf16x8 a, bf16x8 b, f32x4 c) {
    return __builtin_amdgcn_mfma_f32_16x16x32_bf16(a, b, c, 0, 0, 0);
}
__device__ __forceinline__ unsigned fkey(float f) {
    unsigned u = __builtin_bit_cast(unsigned, f);
    return (u & 0x80000000u) ? ~u : (u | 0x80000000u);
}
__device__ __forceinline__ float funkey(unsigned k) {
    unsigned u = (k & 0x80000000u) ? (k ^ 0x80000000u) : ~k;
    return __builtin_bit_cast(float, u);
}

// ---------------- prep: cvts, mbA (A-fragment-order masks), weight T ---------
// mbA[g][jt][w]: bit b = adj(g*16+(b&15), jt*64+(b>>4)*8+(w>>3)*32+(w&7)) > 0
__global__ __launch_bounds__(256) void prep(
    const int* __restrict__ adj, u64* __restrict__ mbA, unsigned* __restrict__ gmk,
    const float* __restrict__ x, u16* __restrict__ xB,
    const float* __restrict__ W1, u16* __restrict__ W1B,
    const float* __restrict__ W, const float* __restrict__ Wo,
    u16* __restrict__ WBt, u16* __restrict__ WoBt) {
    __shared__ alignas(16) u16 T[64][72];
    const int bid = blockIdx.x, t = threadIdx.x;
    if (bid < 4096) {
        int i = bid * 256 + t;
        const float* s;
        u16* d;
        if (i < N_NODES * FIN / 4) { s = x; d = xB; }
        else { i -= N_NODES * FIN / 4; s = W1; d = W1B; }
        float4 v = ((const float4*)s)[i];
        ushort4 o = {bf16u(v.x), bf16u(v.y), bf16u(v.z), bf16u(v.w)};
        ((ushort4*)d)[i] = o;
    } else if (bid < 8192) {
        if (bid == 4096 && t < 16) gmk[t] = 0u;
        const int lane = t & 63;
        const int task = (bid - 4096) * 4 + (t >> 6);  // (g, jt)
        const int g = task >> 6, jt = task & 63;
        const int r = lane & 15, kq = lane >> 4;
        const int* ap = adj + (size_t)(g * 16 + r) * N_NODES + jt * 64 + kq * 8;
        int4 c0 = *(const int4*)(ap);
        int4 c1 = *(const int4*)(ap + 4);
        int4 c2 = *(const int4*)(ap + 32);
        int4 c3 = *(const int4*)(ap + 36);
        u64 myw = 0;
        #pragma unroll
        for (int w = 0; w < 16; ++w) {
            const int hf = w >> 3, i = w & 7;
            int val;
            if (hf == 0) val = (i < 4) ? ((const int*)&c0)[i & 3] : ((const int*)&c1)[i & 3];
            else         val = (i < 4) ? ((const int*)&c2)[i & 3] : ((const int*)&c3)[i & 3];
            u64 bal = __ballot(val > 0);
            if (lane == w) myw = bal;
        }
        if (lane < 16) mbA[((size_t)g * 64 + jt) * 16 + lane] = myw;
    } else {
        int idx = bid - 8192;
        int y = idx >> 3, xb = idx & 7;
        const float* src = (y < 8) ? W + (size_t)y * FIN * DHEAD : Wo;
        u16* d = (y < 8) ? WBt + (size_t)y * DHEAD * FIN : WoBt;
        const int j0 = xb * 64;
        const int row = t & 63, g = t >> 6;
        #pragma unroll
        for (int k = 0; k < 16; k += 4) {
            float4 v = *(const float4*)(src + (size_t)(j0 + row) * 64 + g * 16 + k);
            T[g * 16 + k + 0][row] = bf16u(v.x);
            T[g * 16 + k + 1][row] = bf16u(v.y);
            T[g * 16 + k + 2][row] = bf16u(v.z);
            T[g * 16 + k + 3][row] = bf16u(v.w);
        }
        __syncthreads();
        const int dd = t >> 2, jc = (t & 3) * 16;
        *(uint4*)(d + (size_t)dd * FIN + j0 + jc) = *(const uint4*)&T[dd][jc];
        *(uint4*)(d + (size_t)dd * FIN + j0 + jc + 8) = *(const uint4*)&T[dd][jc + 8];
    }
}

// ---------------- fused MFMA GEMM (x@W / h@Wo + f1/f2 + gmax + bf16-T out) ----
__global__ __launch_bounds__(256) void gemm_fused(
    const u16* __restrict__ A, int lda, const u16* __restrict__ Bt, int ldb,
    const float* __restrict__ a1a, const float* __restrict__ a2a,
    u16* __restrict__ WhBT, float* __restrict__ f1o, float* __restrict__ f2o,
    unsigned* __restrict__ gmk, int K) {
    __shared__ alignas(16) u16 T[64][72];
    const int t = threadIdx.x, lane = t & 63, wv = t >> 6;
    const int c16 = lane & 15, kg = lane >> 4;
    const int h = blockIdx.x;
    const int bm = blockIdx.y * 64;
    const u16* Ap = A + (size_t)(bm + wv * 16 + c16) * lda + kg * 8;
    const u16* Bp = Bt + (size_t)(h * 64 + c16) * ldb + kg * 8;
    f32x4 acc[4] = {};
    #pragma unroll 4
    for (int k0 = 0; k0 < K; k0 += 32) {
        bf16x8 a = *(const bf16x8*)(Ap + k0);
        #pragma unroll
        for (int ct = 0; ct < 4; ++ct) {
            bf16x8 b = *(const bf16x8*)(Bp + (size_t)ct * 16 * ldb + k0);
            acc[ct] = mfma16(a, b, acc[ct]);
        }
    }
    float a1v[4], a2v[4];
    #pragma unroll
    for (int ct = 0; ct < 4; ++ct) {
        a1v[ct] = a1a[h * 64 + ct * 16 + c16];
        a2v[ct] = a2a[h * 64 + ct * 16 + c16];
    }
    float mx = -1e30f;
    #pragma unroll
    for (int r = 0; r < 4; ++r) {
        float s1 = 0.f, s2 = 0.f;
        int rl = wv * 16 + kg * 4 + r;
        #pragma unroll
        for (int ct = 0; ct < 4; ++ct) {
            float v = acc[ct][r];
            s1 = fmaf(v, a1v[ct], s1);
            s2 = fmaf(v, a2v[ct], s2);
            T[ct * 16 + c16][rl] = bf16u(v);
        }
        #pragma unroll
        for (int off = 1; off < 16; off <<= 1) {
            s1 += __shfl_xor(s1, off, 64);
            s2 += __shfl_xor(s2, off, 64);
        }
        if (c16 == 0) {
            f1o[(size_t)h * N_NODES + bm + rl] = s1;
            f2o[(size_t)h * N_NODES + bm + rl] = s2;
        }
        mx = fmaxf(mx, s2);
    }
    mx = fmaxf(mx, __shfl_xor(mx, 16, 64));
    mx = fmaxf(mx, __shfl_xor(mx, 32, 64));
    if (lane == 0) atomicMax(&gmk[h], fkey(mx));
    __syncthreads();
    const int dd = t >> 2, jc = (t & 3) * 16;
    u16* dst = WhBT + (size_t)(h * 64 + dd) * N_NODES + bm;
    *(uint4*)(dst + jc) = *(const uint4*)&T[dd][jc];
    *(uint4*)(dst + jc + 8) = *(const uint4*)&T[dd][jc + 8];
}

// ---------------- per-row / per-col softmax coefficients ----------------
__global__ void coefk(const float* __restrict__ f1, const float* __restrict__ f2,
                      const unsigned* __restrict__ gmk, float2* __restrict__ rowc,
                      float2* __restrict__ uv) {
    int h = blockIdx.y;
    int i = blockIdx.x * 256 + threadIdx.x;
    float g = funkey(gmk[h]);
    float a = f1[(size_t)h * N_NODES + i];
    float s = a + g;
    float M = lrelu02(s);
    rowc[(size_t)h * N_NODES + i] = make_float2(__expf(s - M), __expf(0.2f * s - M));
    float b = f2[(size_t)h * N_NODES + i] - g;
    uv[(size_t)h * N_NODES + i] = make_float2(__expf(b), __expf(0.2f * b));
}

// ---------------- attention v6: register-direct, wave-independent ------------
// Wave owns MT*16 rows x 64 cols x its j-range; p built in A-fragment layout;
// no LDS, no barriers. Output: bf16 row-major partial [js][4096][OC].
template <int NH, int MT, int JSPLIT, int LJS>
__global__ __launch_bounds__(256) void attn_v6(
    const u16* __restrict__ WhB, const float2* __restrict__ uv,
    const float2* __restrict__ rowc, const u64* __restrict__ mbA,
    u16* __restrict__ outp, float* __restrict__ denP) {
    constexpr int NJT = 64 / JSPLIT;
    constexpr int OC = (NH == 8) ? 512 : 64;
    const int t = threadIdx.x, lane = t & 63;
    int h, ib, js;
    if (NH == 8) {
        h = blockIdx.x & 7;
        const int wid = __builtin_amdgcn_readfirstlane((blockIdx.x >> 3) * 4 + (t >> 6));
        js = wid & (JSPLIT - 1);
        ib = wid >> LJS;
    } else {
        h = 0;
        const int wid = __builtin_amdgcn_readfirstlane(blockIdx.x * 4 + (t >> 6));
        js = wid & (JSPLIT - 1);
        ib = wid >> LJS;
    }
    const int i0 = ib * (MT * 16);
    const int g0 = i0 >> 4;
    const int jt0 = js * NJT;
    const int kg = lane >> 4, c16 = lane & 15;

    const float* uvf = (const float*)(uv + (size_t)h * N_NODES);
    const float2* rcp = rowc + (size_t)h * N_NODES;

    float Aq[MT], Bq[MT], den[MT];
    #pragma unroll
    for (int mt = 0; mt < MT; ++mt) {
        float2 rc = rcp[i0 + mt * 16 + c16];
        Aq[mt] = rc.x; Bq[mt] = rc.y; den[mt] = 0.f;
    }
    const u16* bp[4];
    #pragma unroll
    for (int ct = 0; ct < 4; ++ct)
        bp[ct] = WhB + ((size_t)h * 64 + ct * 16 + c16) * N_NODES + kg * 8;

    f32x4 acc[MT][4] = {};

    for (int it = 0; it < NJT; ++it) {
        const int jt = jt0 + it;
        const float* up = uvf + (size_t)(jt * 64 + kg * 8) * 2;
        float4 u0[4], u1[4];
        #pragma unroll
        for (int k = 0; k < 4; ++k) {
            u0[k] = *(const float4*)(up + k * 4);
            u1[k] = *(const float4*)(up + 64 + k * 4);
        }
        bf16x8 bfr[4][2];
        #pragma unroll
        for (int ct = 0; ct < 4; ++ct) {
            bfr[ct][0] = *(const bf16x8*)(bp[ct] + (size_t)jt * 64);
            bfr[ct][1] = *(const bf16x8*)(bp[ct] + (size_t)jt * 64 + 32);
        }
        #pragma unroll
        for (int mt = 0; mt < MT; ++mt) {
            const u64* mw = mbA + ((size_t)(g0 + mt) * 64 + jt) * 16;
            unsigned pk[8];
            #pragma unroll
            for (int hf = 0; hf < 2; ++hf) {
                #pragma unroll
                for (int k = 0; k < 4; ++k) {
                    float4 q = hf ? u1[k] : u0[k];
                    u64 w0 = mw[hf * 8 + 2 * k];
                    u64 w1 = mw[hf * 8 + 2 * k + 1];
                    unsigned l0 = __builtin_amdgcn_readfirstlane((unsigned)w0);
                    unsigned h0 = __builtin_amdgcn_readfirstlane((unsigned)(w0 >> 32));
                    unsigned l1 = __builtin_amdgcn_readfirstlane((unsigned)w1);
                    unsigned h1 = __builtin_amdgcn_readfirstlane((unsigned)(w1 >> 32));
                    u64 ws0 = ((u64)h0 << 32) | l0;
                    u64 ws1 = ((u64)h1 << 32) | l1;
                    float t0 = fmaxf(Aq[mt] * q.x, Bq[mt] * q.y);
                    float t1 = fmaxf(Aq[mt] * q.z, Bq[mt] * q.w);
                    float p0, p1;
                    asm("v_cndmask_b32 %0, 0, %1, %2" : "=v"(p0) : "v"(t0), "s"(ws0));
                    asm("v_cndmask_b32 %0, 0, %1, %2" : "=v"(p1) : "v"(t1), "s"(ws1));
                    den[mt] += p0 + p1;
                    unsigned pkd;
                    asm("v_cvt_pk_bf16_f32 %0, %1, %2" : "=v"(pkd) : "v"(p0), "v"(p1));
                    pk[hf * 4 + k] = pkd;
                }
            }
            union { unsigned d[4]; bf16x8 v; } ua, ub;
            #pragma unroll
            for (int k = 0; k < 4; ++k) { ua.d[k] = pk[k]; ub.d[k] = pk[4 + k]; }
            #pragma unroll
            for (int ct = 0; ct < 4; ++ct) {
                acc[mt][ct] = mfma16(ua.v, bfr[ct][0], acc[mt][ct]);
                acc[mt][ct] = mfma16(ub.v, bfr[ct][1], acc[mt][ct]);
            }
        }
    }

    #pragma unroll
    for (int mt = 0; mt < MT; ++mt) {
        den[mt] += __shfl_xor(den[mt], 16, 64);
        den[mt] += __shfl_xor(den[mt], 32, 64);
    }
    float* denDst = (NH == 8) ? denP + (size_t)js * (8 * N_NODES) + (size_t)h * N_NODES
                              : denP + (size_t)js * N_NODES;
    if (lane < 16) {
        #pragma unroll
        for (int mt = 0; mt < MT; ++mt) denDst[i0 + mt * 16 + lane] = den[mt];
    }
    u16* dst = outp + (size_t)js * N_NODES * OC + h * 64;
    #pragma unroll
    for (int mt = 0; mt < MT; ++mt)
        #pragma unroll
        for (int ct = 0; ct < 4; ++ct)
            #pragma unroll
            for (int r = 0; r < 4; ++r)
                dst[(size_t)(i0 + mt * 16 + kg * 4 + r) * OC + ct * 16 + c16] =
                    bf16u(acc[mt][ct][r]);
}

// ---------------- combine attn8 partials (8-way bf16) -> bf16 hB ----------
__global__ __launch_bounds__(256) void combine8(
    const u16* __restrict__ part, const float* __restrict__ denp,
    u16* __restrict__ hB) {
    const int t4 = (blockIdx.x * 256 + threadIdx.x) * 4;
    const int i = t4 >> 9, c = t4 & 511, h = c >> 6;
    float s[4] = {0.f, 0.f, 0.f, 0.f};
    float d = 0.f;
    #pragma unroll
    for (int js = 0; js < 8; ++js) {
        ushort4 p = *(const ushort4*)(part + (size_t)js * N_NODES * 512 + t4);
        s[0] += b2f(p.x); s[1] += b2f(p.y); s[2] += b2f(p.z); s[3] += b2f(p.w);
        d += denp[(size_t)js * (8 * N_NODES) + h * N_NODES + i];
    }
    float inv = d > 0.f ? 1.f / d : 0.f;
    ushort4 o;
    #pragma unroll
    for (int k = 0; k < 4; ++k) {
        float v = s[k] * inv;
        float e = v > 0.f ? v : expm1f(v);
        ((u16*)&o)[k] = bf16u(e);
    }
    *(ushort4*)(hB + t4) = o;
}

// ---------------- combine attn1 partials (16-way bf16) + ELU -> fp32 T -------
__global__ __launch_bounds__(256) void combine1T(
    const u16* __restrict__ part1, const float* __restrict__ den1,
    float* __restrict__ attoutT) {
    __shared__ float T[64][65];
    const int b = blockIdx.x, t = threadIdx.x;
    const int r0 = b * 64;
    const int rl = t >> 2, cg = (t & 3) * 16;
    const int row = r0 + rl;
    float d = 0.f;
    #pragma unroll
    for (int js = 0; js < 16; ++js) d += den1[(size_t)js * N_NODES + row];
    float inv = d > 0.f ? 1.f / d : 0.f;
    float s[16] = {};
    #pragma unroll
    for (int js = 0; js < 16; ++js) {
        const u16* p = part1 + (size_t)js * N_NODES * 64 + (size_t)row * 64 + cg;
        #pragma unroll
        for (int k = 0; k < 16; k += 4) {
            ushort4 v = *(const ushort4*)(p + k);
            s[k] += b2f(v.x); s[k + 1] += b2f(v.y);
            s[k + 2] += b2f(v.z); s[k + 3] += b2f(v.w);
        }
    }
    #pragma unroll
    for (int k = 0; k < 16; ++k) {
        float e = s[k] * inv;
        T[rl][cg + k] = e > 0.f ? e : expm1f(e);
    }
    __syncthreads();
    const int c = t >> 2, seg = (t & 3) * 16;
    #pragma unroll
    for (int k = 0; k < 16; k += 4) {
        float4 v = {T[seg + k][c], T[seg + k + 1][c], T[seg + k + 2][c], T[seg + k + 3][c]};
        *(float4*)(attoutT + (size_t)c * N_NODES + r0 + seg + k) = v;
    }
}

// ---------------- row log_softmax on attoutT, emit bf16 lsT ----------------
__global__ __launch_bounds__(256) void lsm_row(const float* __restrict__ aT,
                                               u16* __restrict__ lsT) {
    int c = blockIdx.x, t = threadIdx.x;
    const float* row = aT + (size_t)c * N_NODES;
    __shared__ float r[256];
    float m = -1e30f;
    for (int i = t * 4; i < N_NODES; i += 1024) {
        float4 v = *(const float4*)(row + i);
        m = fmaxf(fmaxf(fmaxf(m, v.x), fmaxf(v.y, v.z)), v.w);
    }
    r[t] = m;
    __syncthreads();
    for (int s = 128; s; s >>= 1) {
        if (t < s) r[t] = fmaxf(r[t], r[t + s]);
        __syncthreads();
    }
    m = r[0];
    __syncthreads();
    float sum = 0.f;
    for (int i = t * 4; i < N_NODES; i += 1024) {
        float4 v = *(const float4*)(row + i);
        sum += __expf(v.x - m) + __expf(v.y - m) + __expf(v.z - m) + __expf(v.w - m);
    }
    r[t] = sum;
    __syncthreads();
    for (int s = 128; s; s >>= 1) {
        if (t < s) r[t] += r[t + s];
        __syncthreads();
    }
    float lse = m + __logf(r[0]);
    for (int i = t * 4; i < N_NODES; i += 1024) {
        float4 v = *(const float4*)(row + i);
        ushort4 o = {bf16u(v.x - lse), bf16u(v.y - lse), bf16u(v.z - lse), bf16u(v.w - lse)};
        *(ushort4*)(lsT + (size_t)c * N_NODES + i) = o;
    }
}

// ---------------- mlp1: split-K MFMA  part[ks][64 c][512 o] ----------------
__global__ __launch_bounds__(256) void mlp1_mfma(
    const u16* __restrict__ lsT, const u16* __restrict__ W1B,
    float* __restrict__ part) {
    const int t = threadIdx.x, lane = t & 63, wv = t >> 6;
    const int c16 = lane & 15, kg = lane >> 4;
    const int ks = blockIdx.x & 15;
    const int bn = (blockIdx.x >> 4) * 64;
    const int kb = ks * 256;
    const u16* Ap = lsT + (size_t)(wv * 16 + c16) * N_NODES + kb + kg * 8;
    const u16* Bp = W1B + (size_t)(bn + c16) * N_NODES + kb + kg * 8;
    f32x4 acc[4] = {};
    #pragma unroll
    for (int k0 = 0; k0 < 256; k0 += 32) {
        bf16x8 a = *(const bf16x8*)(Ap + k0);
        #pragma unroll
        for (int ct = 0; ct < 4; ++ct) {
            bf16x8 b = *(const bf16x8*)(Bp + (size_t)ct * 16 * N_NODES + k0);
            acc[ct] = mfma16(a, b, acc[ct]);
        }
    }
    float* dst = part + (size_t)ks * 64 * 512;
    #pragma unroll
    for (int ct = 0; ct < 4; ++ct)
        #pragma unroll
        for (int r = 0; r < 4; ++r)
            dst[(size_t)(wv * 16 + kg * 4 + r) * 512 + bn + ct * 16 + c16] = acc[ct][r];
}

// ---------------- fused: reduce split-K + bias + leaky, then y @ W2^T --------
__global__ __launch_bounds__(256) void mlp2f(
    const float* __restrict__ part, const float* __restrict__ b1,
    const float* __restrict__ W2, const float* __restrict__ b2,
    float* __restrict__ out) {
    __shared__ alignas(16) float row[512];
    const int c = blockIdx.x, t = threadIdx.x;
    #pragma unroll
    for (int half = 0; half < 2; ++half) {
        int o = t + half * 256;
        float s = 0.f;
        #pragma unroll
        for (int ks = 0; ks < 16; ++ks)
            s += part[(size_t)ks * 32768 + (size_t)c * 512 + o];
        s += b1[o];
        row[o] = s > 0.f ? s : 0.1f * s;
    }
    __syncthreads();
    float acc = 0.f;
    #pragma unroll 4
    for (int o = 0; o < 512; o += 4) {
        float4 w4 = *(const float4*)(W2 + (size_t)t * 512 + o);
        float4 r4 = *(const float4*)(&row[o]);
        acc += w4.x * r4.x + w4.y * r4.y + w4.z * r4.z + w4.w * r4.w;
    }
    out[(size_t)c * 256 + t] = acc + b2[t];
}

extern "C" void kernel_launch(void* const* d_in, const int* in_sizes, int n_in,
                              void* d_out, int out_size, void* d_ws, size_t ws_size,
                              hipStream_t stream) {
    const float* x   = (const float*)d_in[0];
    const int*   adj = (const int*)d_in[1];
    const float* W   = (const float*)d_in[2];
    const float* a1  = (const float*)d_in[3];
    const float* a2  = (const float*)d_in[4];
    const float* Wo  = (const float*)d_in[5];
    const float* ao1 = (const float*)d_in[6];
    const float* ao2 = (const float*)d_in[7];
    const float* W1  = (const float*)d_in[8];
    const float* b1  = (const float*)d_in[9];
    const float* W2  = (const float*)d_in[10];
    const float* b2  = (const float*)d_in[11];
    float* out = (float*)d_out;

    char* ws = (char*)d_ws;
    size_t off = 0;
    auto alloc = [&](size_t bytes) {
        void* p = ws + off;
        off += (bytes + 255) & ~(size_t)255;
        return p;
    };
    u64*     mbA    = (u64*)alloc((size_t)256 * 64 * 16 * 8);          // 2 MB
    u16*     xB     = (u16*)alloc((size_t)N_NODES * FIN * 2);
    u16*     WBt    = (u16*)alloc((size_t)NHEAD * DHEAD * FIN * 2);
    u16*     WoBt   = (u16*)alloc((size_t)DHEAD * FIN * 2);
    u16*     W1B    = (u16*)alloc((size_t)512 * N_NODES * 2);
    u16*     WhB    = (u16*)alloc((size_t)NHEAD * DHEAD * N_NODES * 2);
    u16*     WhoB   = (u16*)alloc((size_t)DHEAD * N_NODES * 2);
    u16*     hB     = (u16*)alloc((size_t)N_NODES * 512 * 2);
    u16*     part8  = (u16*)alloc((size_t)8 * N_NODES * 512 * 2);      // 32 MB bf16
    float*   den8   = (float*)alloc((size_t)8 * 8 * N_NODES * 4);      // 1 MB
    float*   f1b    = (float*)alloc((size_t)9 * N_NODES * 4);
    float*   f2b    = (float*)alloc((size_t)9 * N_NODES * 4);
    unsigned* gmk   = (unsigned*)alloc(16 * 4);
    float2*  rowc   = (float2*)alloc((size_t)9 * N_NODES * 8);
    float2*  uvb    = (float2*)alloc((size_t)9 * N_NODES * 8);
    // layer-2 scratch overlaid on part8 (dead after combine8)
    char*  ov      = (char*)part8;
    u16*   part1   = (u16*)(ov);                            // 8 MB [16][4096][64] bf16
    float* den1    = (float*)(ov + ((size_t)8 << 20));      // 256 KB
    float* attoutT = (float*)(ov + ((size_t)9 << 20));      // 1 MB
    u16*   lsT     = (u16*)(ov + ((size_t)10 << 20));       // 512 KB
    float* part    = (float*)(ov + ((size_t)11 << 20));     // 2 MB
    (void)ws_size; (void)in_sizes; (void)n_in; (void)out_size;

    prep<<<8264, 256, 0, stream>>>(adj, mbA, gmk, x, xB, W1, W1B, W, Wo, WBt, WoBt);
    // layer 1
    gemm_fused<<<dim3(8, 64), 256, 0, stream>>>(xB, FIN, WBt, FIN, a1, a2,
                                                WhB, f1b, f2b, gmk, FIN);
    coefk<<<dim3(16, 8), 256, 0, stream>>>(f1b, f2b, gmk, rowc, uvb);
    // 8192 waves: h = bid&7 (XCD-pinned), 8 js x 128 ib (32 rows)
    attn_v6<8, 2, 8, 3><<<2048, 256, 0, stream>>>(WhB, uvb, rowc, mbA, part8, den8);
    combine8<<<N_NODES * 512 / 4 / 256, 256, 0, stream>>>(part8, den8, hB);
    // layer 2
    gemm_fused<<<dim3(1, 64), 256, 0, stream>>>(hB, 512, WoBt, FIN, ao1, ao2,
                                                WhoB, f1b + (size_t)8 * N_NODES,
                                                f2b + (size_t)8 * N_NODES, gmk + 8, FIN);
    coefk<<<dim3(16, 1), 256, 0, stream>>>(f1b + (size_t)8 * N_NODES,
                                           f2b + (size_t)8 * N_NODES, gmk + 8,
                                           rowc + (size_t)8 * N_NODES,
                                           uvb + (size_t)8 * N_NODES);
    // 4096 waves: 16 js x 256 ib (16 rows)
    attn_v6<1, 1, 16, 4><<<1024, 256, 0, stream>>>(
        WhoB, uvb + (size_t)8 * N_NODES, rowc + (size_t)8 * N_NODES, mbA, part1, den1);
    combine1T<<<64, 256, 0, stream>>>(part1, den1, attoutT);
    lsm_row<<<64, 256, 0, stream>>>(attoutT, lsT);
    // MLP head
    mlp1_mfma<<<128, 256, 0, stream>>>(lsT, W1B, part);
    mlp2f<<<64, 256, 0, stream>>>(part, b1, W2, b2, out);
}

// Round 13
// 201.379 us; speedup vs baseline: 1.1881x; 1.1660x over previous
//
#include <hip/hip_runtime.h>
#include <hip/hip_bf16.h>
#include <math.h>

// GAT forward. N=4096, Fin=512, H=8, D=64, C=64.
// Round 13: best-known assembly. Attention = round-7 attn_v3 verbatim (57us,
// prefetch+1-barrier — rounds 8-12's variants all regressed). Plus the fusions
// that survived: prep mega-kernel (pack+cvt+wT, -4 launches), mlp2f (-1).
// 11 launches total.

#define N_NODES 4096
#define FIN 512
#define NHEAD 8
#define DHEAD 64
#define NCLS 64
#define NW 64

typedef unsigned short u16;
typedef unsigned long long u64;
typedef __attribute__((ext_vector_type(8))) short bf16x8;
typedef __attribute__((ext_vector_type(4))) float f32x4;

__device__ __forceinline__ float lrelu02(float x) { return x > 0.f ? x : 0.2f * x; }
__device__ __forceinline__ u16 bf16u(float x) {
    __hip_bfloat16 h = __float2bfloat16(x);
    return __builtin_bit_cast(unsigned short, h);
}
__device__ __forceinline__ f32x4 mfma16(bf16x8 a, bf16x8 b, f32x4 c) {
    return __builtin_amdgcn_mfma_f32_16x16x32_bf16(a, b, c, 0, 0, 0);
}
__device__ __forceinline__ unsigned fkey(float f) {
    unsigned u = __builtin_bit_cast(unsigned, f);
    return (u & 0x80000000u) ? ~u : (u | 0x80000000u);
}
__device__ __forceinline__ float funkey(unsigned k) {
    unsigned u = (k & 0x80000000u) ? (k ^ 0x80000000u) : ~k;
    return __builtin_bit_cast(float, u);
}

// ---------------- prep: pack adj -> mb[row][jword], bf16 cvts, weight T ------
__global__ __launch_bounds__(256) void prep(
    const int* __restrict__ adj, u64* __restrict__ mb, unsigned* __restrict__ gmk,
    const float* __restrict__ x, u16* __restrict__ xB,
    const float* __restrict__ W1, u16* __restrict__ W1B,
    const float* __restrict__ W, const float* __restrict__ Wo,
    u16* __restrict__ WBt, u16* __restrict__ WoBt) {
    __shared__ alignas(16) u16 T[64][72];
    const int bid = blockIdx.x, t = threadIdx.x;
    if (bid < 1024) {
        // pack_mask (v3 layout: mb[i*64 + jword])
        if (bid == 0 && t < 16) gmk[t] = 0u;
        int nwaves = (1024 * 256) >> 6;
        int wid = (bid * 256 + t) >> 6;
        int lane = t & 63;
        for (int w = wid; w < N_NODES * NW; w += nwaves) {
            int i = w >> 6, wc = w & 63;
            int j = (wc << 6) | lane;
            u64 m = __ballot(adj[(size_t)i * N_NODES + j] > 0);
            if (lane == 0) mb[w] = m;
        }
    } else if (bid < 5120) {
        // bf16 converts: x then W1
        int i = (bid - 1024) * 256 + t;
        const float* s;
        u16* d;
        if (i < N_NODES * FIN / 4) { s = x; d = xB; }
        else { i -= N_NODES * FIN / 4; s = W1; d = W1B; }
        float4 v = ((const float4*)s)[i];
        ushort4 o = {bf16u(v.x), bf16u(v.y), bf16u(v.z), bf16u(v.w)};
        ((ushort4*)d)[i] = o;
    } else {
        // weight transposes: W[8][512][64] and Wo[512][64] -> [d][k] bf16
        int idx = bid - 5120;
        int y = idx >> 3, xb = idx & 7;
        const float* src = (y < 8) ? W + (size_t)y * FIN * DHEAD : Wo;
        u16* d = (y < 8) ? WBt + (size_t)y * DHEAD * FIN : WoBt;
        const int j0 = xb * 64;
        const int row = t & 63, g = t >> 6;
        #pragma unroll
        for (int k = 0; k < 16; k += 4) {
            float4 v = *(const float4*)(src + (size_t)(j0 + row) * 64 + g * 16 + k);
            T[g * 16 + k + 0][row] = bf16u(v.x);
            T[g * 16 + k + 1][row] = bf16u(v.y);
            T[g * 16 + k + 2][row] = bf16u(v.z);
            T[g * 16 + k + 3][row] = bf16u(v.w);
        }
        __syncthreads();
        const int dd = t >> 2, jc = (t & 3) * 16;
        *(uint4*)(d + (size_t)dd * FIN + j0 + jc) = *(const uint4*)&T[dd][jc];
        *(uint4*)(d + (size_t)dd * FIN + j0 + jc + 8) = *(const uint4*)&T[dd][jc + 8];
    }
}

// ---------------- fused MFMA GEMM (x@W / h@Wo + f1/f2 + gmax + bf16-T out) ----
__global__ __launch_bounds__(256) void gemm_fused(
    const u16* __restrict__ A, int lda, const u16* __restrict__ Bt, int ldb,
    const float* __restrict__ a1a, const float* __restrict__ a2a,
    u16* __restrict__ WhBT, float* __restrict__ f1o, float* __restrict__ f2o,
    unsigned* __restrict__ gmk, int K) {
    __shared__ alignas(16) u16 T[64][72];
    const int t = threadIdx.x, lane = t & 63, wv = t >> 6;
    const int c16 = lane & 15, kg = lane >> 4;
    const int h = blockIdx.x;
    const int bm = blockIdx.y * 64;
    const u16* Ap = A + (size_t)(bm + wv * 16 + c16) * lda + kg * 8;
    const u16* Bp = Bt + (size_t)(h * 64 + c16) * ldb + kg * 8;
    f32x4 acc[4] = {};
    #pragma unroll 4
    for (int k0 = 0; k0 < K; k0 += 32) {
        bf16x8 a = *(const bf16x8*)(Ap + k0);
        #pragma unroll
        for (int ct = 0; ct < 4; ++ct) {
            bf16x8 b = *(const bf16x8*)(Bp + (size_t)ct * 16 * ldb + k0);
            acc[ct] = mfma16(a, b, acc[ct]);
        }
    }
    float a1v[4], a2v[4];
    #pragma unroll
    for (int ct = 0; ct < 4; ++ct) {
        a1v[ct] = a1a[h * 64 + ct * 16 + c16];
        a2v[ct] = a2a[h * 64 + ct * 16 + c16];
    }
    float mx = -1e30f;
    #pragma unroll
    for (int r = 0; r < 4; ++r) {
        float s1 = 0.f, s2 = 0.f;
        int rl = wv * 16 + kg * 4 + r;
        #pragma unroll
        for (int ct = 0; ct < 4; ++ct) {
            float v = acc[ct][r];
            s1 = fmaf(v, a1v[ct], s1);
            s2 = fmaf(v, a2v[ct], s2);
            T[ct * 16 + c16][rl] = bf16u(v);
        }
        #pragma unroll
        for (int off = 1; off < 16; off <<= 1) {
            s1 += __shfl_xor(s1, off, 64);
            s2 += __shfl_xor(s2, off, 64);
        }
        if (c16 == 0) {
            f1o[(size_t)h * N_NODES + bm + rl] = s1;
            f2o[(size_t)h * N_NODES + bm + rl] = s2;
        }
        mx = fmaxf(mx, s2);
    }
    mx = fmaxf(mx, __shfl_xor(mx, 16, 64));
    mx = fmaxf(mx, __shfl_xor(mx, 32, 64));
    if (lane == 0) atomicMax(&gmk[h], fkey(mx));
    __syncthreads();
    const int dd = t >> 2, jc = (t & 3) * 16;
    u16* dst = WhBT + (size_t)(h * 64 + dd) * N_NODES + bm;
    *(uint4*)(dst + jc) = *(const uint4*)&T[dd][jc];
    *(uint4*)(dst + jc + 8) = *(const uint4*)&T[dd][jc + 8];
}

// ---------------- per-row / per-col softmax coefficients ----------------
__global__ void coefk(const float* __restrict__ f1, const float* __restrict__ f2,
                      const unsigned* __restrict__ gmk, float4* __restrict__ rowc,
                      float2* __restrict__ uv) {
    int h = blockIdx.y;
    int i = blockIdx.x * 256 + threadIdx.x;
    float g = funkey(gmk[h]);
    float a = f1[(size_t)h * N_NODES + i];
    float s = a + g;
    float M = lrelu02(s);
    rowc[(size_t)h * N_NODES + i] = make_float4(__expf(s - M), __expf(0.2f * s - M), 0.f, 0.f);
    float b = f2[(size_t)h * N_NODES + i] - g;
    uv[(size_t)h * N_NODES + i] = make_float2(__expf(b), __expf(0.2f * b));
}

// ---------------- attention v3 (round-7, proven): prefetch, j-split ----------
// OUTF 1: fp32 row-major partial [js][4096][512] (NH=8)
// OUTF 3: fp32 transposed partial [js][64][4096]  (NH=1)
template <int NH, int ROWS, int JSPLIT, int OUTF>
__global__ __launch_bounds__(256) void attn_v3(
    const u16* __restrict__ WhB, const float2* __restrict__ uv,
    const float4* __restrict__ rowc, const u64* __restrict__ mb,
    float* __restrict__ outp, float* __restrict__ denP) {
    constexpr int NQ = ROWS / 4;
    constexpr int NMT = ROWS / 16;
    constexpr int NJT = (N_NODES / 64) / JSPLIT;
    __shared__ alignas(16) u16 pS[2][ROWS][64];
    __shared__ float Tof[(OUTF == 3) ? 64 * (ROWS + 1) : 1];
    const int b = blockIdx.x;
    int h, ib, js;
    if (NH == 8) { h = b & 7; int r = b >> 3; js = r % JSPLIT; ib = r / JSPLIT; }
    else { h = 0; js = b % JSPLIT; ib = b / JSPLIT; }
    const int i0 = ib * ROWS;
    const int jt0 = js * NJT;
    const int t = threadIdx.x, lane = t & 63, wv = t >> 6;
    const int wv_u = __builtin_amdgcn_readfirstlane(wv);

    const float2* __restrict__ uvp = uv + (size_t)h * N_NODES;
    const float4* __restrict__ rcp = rowc + (size_t)h * N_NODES;
    const u64* __restrict__ mbp = mb + (size_t)(i0 + wv_u) * NW + jt0;

    float Aq[NQ], Bq[NQ], den[NQ];
    #pragma unroll
    for (int q = 0; q < NQ; ++q) {
        float4 rc = rcp[i0 + q * 4 + wv];
        Aq[q] = rc.x; Bq[q] = rc.y; den[q] = 0.f;
    }
    const int wcE = lane ^ (wv << 3);
    const int wcO = lane ^ ((wv + 4) << 3);
    const int kg = lane >> 4, c16 = lane & 15;
    const int ocol = wv * 16 + c16;
    const u16* bptr = WhB + ((size_t)h * 64 + ocol) * N_NODES + jt0 * 64 + kg * 8;
    const int sw8 = (c16 & 7) << 3;
    f32x4 acc[NMT] = {};

    bf16x8 b0 = *(const bf16x8*)(bptr);
    bf16x8 b1 = *(const bf16x8*)(bptr + 32);
    float2 uvv = uvp[jt0 * 64 + lane];
    u64 m[NQ];
    #pragma unroll
    for (int q = 0; q < NQ; ++q) m[q] = mbp[q * 4 * NW];

    for (int it = 0; it < NJT; ++it) {
        const int buf = it & 1;
        const int nit = (it + 1 < NJT) ? it + 1 : it;
        bf16x8 nb0 = *(const bf16x8*)(bptr + (size_t)nit * 64);
        bf16x8 nb1 = *(const bf16x8*)(bptr + (size_t)nit * 64 + 32);
        float2 nuv = uvp[(jt0 + nit) * 64 + lane];
        u64 nm[NQ];
        #pragma unroll
        for (int q = 0; q < NQ; ++q) nm[q] = mbp[q * 4 * NW + nit];
        #pragma unroll
        for (int q = 0; q < NQ; ++q) {
            unsigned wlo = __builtin_amdgcn_readfirstlane((unsigned)m[q]);
            unsigned whi = __builtin_amdgcn_readfirstlane((unsigned)(m[q] >> 32));
            u64 ws = ((u64)whi << 32) | wlo;
            float tv = fmaxf(Aq[q] * uvv.x, Bq[q] * uvv.y);
            float p;
            asm("v_cndmask_b32 %0, 0, %1, %2" : "=v"(p) : "v"(tv), "s"(ws));
            den[q] += p;
            pS[buf][q * 4 + wv][(q & 1) ? wcO : wcE] = bf16u(p);
        }
        __syncthreads();
        __builtin_amdgcn_s_setprio(1);
        #pragma unroll
        for (int mt = 0; mt < NMT; ++mt) {
            const u16* ap = &pS[buf][mt * 16 + c16][0];
            bf16x8 a0 = *(const bf16x8*)&ap[(kg * 8) ^ sw8];
            bf16x8 a1 = *(const bf16x8*)&ap[(32 + kg * 8) ^ sw8];
            acc[mt] = mfma16(a0, b0, acc[mt]);
            acc[mt] = mfma16(a1, b1, acc[mt]);
        }
        __builtin_amdgcn_s_setprio(0);
        b0 = nb0; b1 = nb1; uvv = nuv;
        #pragma unroll
        for (int q = 0; q < NQ; ++q) m[q] = nm[q];
    }

    #pragma unroll
    for (int q = 0; q < NQ; ++q) {
        float s = den[q];
        #pragma unroll
        for (int off = 32; off; off >>= 1) s += __shfl_xor(s, off, 64);
        den[q] = s;
    }

    if constexpr (OUTF == 1) {
        if (lane == 0) {
            #pragma unroll
            for (int q = 0; q < NQ; ++q)
                denP[(size_t)js * (8 * N_NODES) + (size_t)h * N_NODES + i0 + q * 4 + wv] = den[q];
        }
        float* dst = outp + (size_t)js * N_NODES * 512;
        #pragma unroll
        for (int mt = 0; mt < NMT; ++mt)
            #pragma unroll
            for (int r = 0; r < 4; ++r)
                dst[(size_t)(i0 + mt * 16 + kg * 4 + r) * 512 + h * 64 + ocol] = acc[mt][r];
    } else {
        if (lane == 0) {
            #pragma unroll
            for (int q = 0; q < NQ; ++q)
                denP[(size_t)js * N_NODES + i0 + q * 4 + wv] = den[q];
        }
        #pragma unroll
        for (int mt = 0; mt < NMT; ++mt)
            #pragma unroll
            for (int r = 0; r < 4; ++r)
                Tof[ocol * (ROWS + 1) + mt * 16 + kg * 4 + r] = acc[mt][r];
        __syncthreads();
        const int c = t >> 2, r0 = (t & 3) * 8;
        float* dst = outp + (size_t)js * 64 * N_NODES + (size_t)c * N_NODES + i0 + r0;
        float4 v0 = {Tof[c * (ROWS + 1) + r0 + 0], Tof[c * (ROWS + 1) + r0 + 1],
                     Tof[c * (ROWS + 1) + r0 + 2], Tof[c * (ROWS + 1) + r0 + 3]};
        float4 v1 = {Tof[c * (ROWS + 1) + r0 + 4], Tof[c * (ROWS + 1) + r0 + 5],
                     Tof[c * (ROWS + 1) + r0 + 6], Tof[c * (ROWS + 1) + r0 + 7]};
        *(float4*)(dst) = v0;
        *(float4*)(dst + 4) = v1;
    }
}

// ---------------- combine attn8 partials (2-way) -> bf16 hB ----------------
__global__ __launch_bounds__(256) void combine8(
    const float* __restrict__ part, const float* __restrict__ denp,
    u16* __restrict__ hB) {
    const int t4 = (blockIdx.x * 256 + threadIdx.x) * 4;
    const int i = t4 >> 9, c = t4 & 511, h = c >> 6;
    float4 p0 = *(const float4*)(part + t4);
    float4 p1 = *(const float4*)(part + (size_t)N_NODES * 512 + t4);
    float d = denp[h * N_NODES + i] + denp[8 * N_NODES + h * N_NODES + i];
    float inv = d > 0.f ? 1.f / d : 0.f;
    float v[4] = {(p0.x + p1.x) * inv, (p0.y + p1.y) * inv,
                  (p0.z + p1.z) * inv, (p0.w + p1.w) * inv};
    ushort4 o;
    #pragma unroll
    for (int k = 0; k < 4; ++k) {
        float e = v[k] > 0.f ? v[k] : expm1f(v[k]);
        ((u16*)&o)[k] = bf16u(e);
    }
    *(ushort4*)(hB + t4) = o;
}

// ---------------- combine attn1 partials (4-way) + ELU + log_softmax ---------
__global__ __launch_bounds__(256) void combine1_lsm(
    const float* __restrict__ partT, const float* __restrict__ denp,
    u16* __restrict__ lsT) {
    __shared__ float vb[N_NODES];
    __shared__ float r[256];
    const int c = blockIdx.x, t = threadIdx.x;
    float m = -1e30f;
    for (int i = t * 4; i < N_NODES; i += 1024) {
        float4 s = {0.f, 0.f, 0.f, 0.f}, d = {0.f, 0.f, 0.f, 0.f};
        #pragma unroll
        for (int js = 0; js < 4; ++js) {
            float4 pv = *(const float4*)(partT + (size_t)js * 64 * N_NODES +
                                         (size_t)c * N_NODES + i);
            float4 dv = *(const float4*)(denp + (size_t)js * N_NODES + i);
            s.x += pv.x; s.y += pv.y; s.z += pv.z; s.w += pv.w;
            d.x += dv.x; d.y += dv.y; d.z += dv.z; d.w += dv.w;
        }
        float vv[4] = {d.x > 0.f ? s.x / d.x : 0.f, d.y > 0.f ? s.y / d.y : 0.f,
                       d.z > 0.f ? s.z / d.z : 0.f, d.w > 0.f ? s.w / d.w : 0.f};
        #pragma unroll
        for (int k = 0; k < 4; ++k) {
            float e = vv[k] > 0.f ? vv[k] : expm1f(vv[k]);
            vb[i + k] = e;
            m = fmaxf(m, e);
        }
    }
    r[t] = m;
    __syncthreads();
    for (int s = 128; s; s >>= 1) {
        if (t < s) r[t] = fmaxf(r[t], r[t + s]);
        __syncthreads();
    }
    m = r[0];
    __syncthreads();
    float sum = 0.f;
    for (int i = t; i < N_NODES; i += 256) sum += __expf(vb[i] - m);
    r[t] = sum;
    __syncthreads();
    for (int s = 128; s; s >>= 1) {
        if (t < s) r[t] += r[t + s];
        __syncthreads();
    }
    float lse = m + __logf(r[0]);
    for (int i = t * 4; i < N_NODES; i += 1024) {
        ushort4 o = {bf16u(vb[i] - lse), bf16u(vb[i + 1] - lse),
                     bf16u(vb[i + 2] - lse), bf16u(vb[i + 3] - lse)};
        *(ushort4*)(lsT + (size_t)c * N_NODES + i) = o;
    }
}

// ---------------- mlp1: split-K MFMA  part[ks][64 c][512 o] ----------------
__global__ __launch_bounds__(256) void mlp1_mfma(
    const u16* __restrict__ lsT, const u16* __restrict__ W1B,
    float* __restrict__ part) {
    const int t = threadIdx.x, lane = t & 63, wv = t >> 6;
    const int c16 = lane & 15, kg = lane >> 4;
    const int ks = blockIdx.x & 15;
    const int bn = (blockIdx.x >> 4) * 64;
    const int kb = ks * 256;
    const u16* Ap = lsT + (size_t)(wv * 16 + c16) * N_NODES + kb + kg * 8;
    const u16* Bp = W1B + (size_t)(bn + c16) * N_NODES + kb + kg * 8;
    f32x4 acc[4] = {};
    #pragma unroll
    for (int k0 = 0; k0 < 256; k0 += 32) {
        bf16x8 a = *(const bf16x8*)(Ap + k0);
        #pragma unroll
        for (int ct = 0; ct < 4; ++ct) {
            bf16x8 b = *(const bf16x8*)(Bp + (size_t)ct * 16 * N_NODES + k0);
            acc[ct] = mfma16(a, b, acc[ct]);
        }
    }
    float* dst = part + (size_t)ks * 64 * 512;
    #pragma unroll
    for (int ct = 0; ct < 4; ++ct)
        #pragma unroll
        for (int r = 0; r < 4; ++r)
            dst[(size_t)(wv * 16 + kg * 4 + r) * 512 + bn + ct * 16 + c16] = acc[ct][r];
}

// ---------------- fused: reduce split-K + bias + leaky, then y @ W2^T --------
__global__ __launch_bounds__(256) void mlp2f(
    const float* __restrict__ part, const float* __restrict__ b1,
    const float* __restrict__ W2, const float* __restrict__ b2,
    float* __restrict__ out) {
    __shared__ alignas(16) float row[512];
    const int c = blockIdx.x, t = threadIdx.x;
    #pragma unroll
    for (int half = 0; half < 2; ++half) {
        int o = t + half * 256;
        float s = 0.f;
        #pragma unroll
        for (int ks = 0; ks < 16; ++ks)
            s += part[(size_t)ks * 32768 + (size_t)c * 512 + o];
        s += b1[o];
        row[o] = s > 0.f ? s : 0.1f * s;
    }
    __syncthreads();
    float acc = 0.f;
    #pragma unroll 4
    for (int o = 0; o < 512; o += 4) {
        float4 w4 = *(const float4*)(W2 + (size_t)t * 512 + o);
        float4 r4 = *(const float4*)(&row[o]);
        acc += w4.x * r4.x + w4.y * r4.y + w4.z * r4.z + w4.w * r4.w;
    }
    out[(size_t)c * 256 + t] = acc + b2[t];
}

extern "C" void kernel_launch(void* const* d_in, const int* in_sizes, int n_in,
                              void* d_out, int out_size, void* d_ws, size_t ws_size,
                              hipStream_t stream) {
    const float* x   = (const float*)d_in[0];
    const int*   adj = (const int*)d_in[1];
    const float* W   = (const float*)d_in[2];
    const float* a1  = (const float*)d_in[3];
    const float* a2  = (const float*)d_in[4];
    const float* Wo  = (const float*)d_in[5];
    const float* ao1 = (const float*)d_in[6];
    const float* ao2 = (const float*)d_in[7];
    const float* W1  = (const float*)d_in[8];
    const float* b1  = (const float*)d_in[9];
    const float* W2  = (const float*)d_in[10];
    const float* b2  = (const float*)d_in[11];
    float* out = (float*)d_out;

    char* ws = (char*)d_ws;
    size_t off = 0;
    auto alloc = [&](size_t bytes) {
        void* p = ws + off;
        off += (bytes + 255) & ~(size_t)255;
        return p;
    };
    u64*     mb     = (u64*)alloc((size_t)N_NODES * NW * 8);
    u16*     xB     = (u16*)alloc((size_t)N_NODES * FIN * 2);
    u16*     WBt    = (u16*)alloc((size_t)NHEAD * DHEAD * FIN * 2);
    u16*     WoBt   = (u16*)alloc((size_t)DHEAD * FIN * 2);
    u16*     W1B    = (u16*)alloc((size_t)512 * N_NODES * 2);
    u16*     WhB    = (u16*)alloc((size_t)NHEAD * DHEAD * N_NODES * 2);
    u16*     WhoB   = (u16*)alloc((size_t)DHEAD * N_NODES * 2);
    u16*     hB     = (u16*)alloc((size_t)N_NODES * 512 * 2);
    float*   part8  = (float*)alloc((size_t)2 * N_NODES * 512 * 4);   // 16 MB
    float*   den8   = (float*)alloc((size_t)2 * 8 * N_NODES * 4);
    float*   f1b    = (float*)alloc((size_t)9 * N_NODES * 4);
    float*   f2b    = (float*)alloc((size_t)9 * N_NODES * 4);
    unsigned* gmk   = (unsigned*)alloc(16 * 4);
    float4*  rowc   = (float4*)alloc((size_t)9 * N_NODES * 16);
    float2*  uvb    = (float2*)alloc((size_t)9 * N_NODES * 8);
    // layer-2 scratch overlaid on part8 (dead after combine8)
    char*    ov     = (char*)part8;
    float*   partT1 = (float*)(ov);                                    // 4 MB [4][64][4096]
    float*   den1   = (float*)(ov + ((size_t)4 << 20));                // 64 KB
    u16*     lsT    = (u16*)(ov + ((size_t)4 << 20) + (256 << 10));    // 512 KB
    float*   part   = (float*)(ov + ((size_t)5 << 20));                // 2 MB
    (void)ws_size; (void)in_sizes; (void)n_in; (void)out_size;

    prep<<<5192, 256, 0, stream>>>(adj, mb, gmk, x, xB, W1, W1B, W, Wo, WBt, WoBt);
    // layer 1
    gemm_fused<<<dim3(8, 64), 256, 0, stream>>>(xB, FIN, WBt, FIN, a1, a2,
                                                WhB, f1b, f2b, gmk, FIN);
    coefk<<<dim3(16, 8), 256, 0, stream>>>(f1b, f2b, gmk, rowc, uvb);
    attn_v3<8, 64, 2, 1><<<(N_NODES / 64) * 2 * 8, 256, 0, stream>>>(
        WhB, uvb, rowc, mb, part8, den8);
    combine8<<<N_NODES * 512 / 4 / 256, 256, 0, stream>>>(part8, den8, hB);
    // layer 2
    gemm_fused<<<dim3(1, 64), 256, 0, stream>>>(hB, 512, WoBt, FIN, ao1, ao2,
                                                WhoB, f1b + (size_t)8 * N_NODES,
                                                f2b + (size_t)8 * N_NODES, gmk + 8, FIN);
    coefk<<<dim3(16, 1), 256, 0, stream>>>(f1b + (size_t)8 * N_NODES,
                                           f2b + (size_t)8 * N_NODES, gmk + 8,
                                           rowc + (size_t)8 * N_NODES,
                                           uvb + (size_t)8 * N_NODES);
    attn_v3<1, 32, 4, 3><<<(N_NODES / 32) * 4, 256, 0, stream>>>(
        WhoB, uvb + (size_t)8 * N_NODES, rowc + (size_t)8 * N_NODES, mb, partT1, den1);
    combine1_lsm<<<64, 256, 0, stream>>>(partT1, den1, lsT);
    // MLP head
    mlp1_mfma<<<128, 256, 0, stream>>>(lsT, W1B, part);
    mlp2f<<<64, 256, 0, stream>>>(part, b1, W2, b2, out);
}